// Round 12
// baseline (142.949 us; speedup 1.0000x reference)
//
#include <hip/hip_runtime.h>

// Problem constants (fixed by setup_inputs): B=64, T=1024, V=128, S=256
constexpr int B_ = 64;
constexpr int T_ = 1024;
constexpr int V_ = 128;
constexpr int S_ = 256;
constexpr int GRING = 32;            // staged rows per direction (8 blocks of 4)
constexpr int ROWF = 384;            // floats per staged row: 3 planes x 64 lanes x float2
constexpr int NGW = 4;               // gather waves per direction
constexpr float INV_LN2 = 1.4426950408889634f;
constexpr float LN2 = 0.6931471805599453f;
constexpr unsigned MAGIC = 0x5AD0F00Du;   // != 0xAAAAAAAA poison, != 0

#define WG_SCOPE __HIP_MEMORY_SCOPE_WORKGROUP
#define AG_SCOPE __HIP_MEMORY_SCOPE_AGENT

// DPP cross-lane move (VALU pipe). old=0, bound_ctrl=false: OOB source -> 0.
template<int CTRL>
__device__ __forceinline__ float dppf(float x) {
    return __int_as_float(__builtin_amdgcn_update_dpp(
        0, __float_as_int(x), CTRL, 0xF, 0xF, false));
}
constexpr int DPP_WAVE_SHR1 = 0x138;   // lane i <- lane i-1 (lane 0 -> 0)
constexpr int DPP_WAVE_SHL1 = 0x130;   // lane i <- lane i+1 (lane 63 -> 0)
constexpr int DPP_ROW_SHR1  = 0x111;
constexpr int DPP_ROW_SHR2  = 0x112;
constexpr int DPP_ROW_SHR4  = 0x114;
constexpr int DPP_ROW_SHR8  = 0x118;
constexpr int DPP_BCAST15   = 0x142;
constexpr int DPP_BCAST31   = 0x143;

__device__ __forceinline__ void poll_eq(int* p, int want) {
    // RELAXED: ds ops retire in order per wave, LDS physically shared ->
    // a visible tag implies the producer's earlier ds_writes retired.
    while (__hip_atomic_load(p, __ATOMIC_RELAXED, WG_SCOPE) != want)
        __builtin_amdgcn_s_sleep(1);
}
__device__ __forceinline__ void poll_ge(int* p, int want) {
    while (__hip_atomic_load(p, __ATOMIC_RELAXED, WG_SCOPE) < want)
        __builtin_amdgcn_s_sleep(1);
}

// Wave-uniform rescale via DPP max-reduce: pin wave max into [2^123, 2^124).
// R8/R10-proven numerics (8-row period; R9's 16-row variant underflows).
__device__ __forceinline__ int wave_rescale(float a[10], int& K) {
    float mx = a[0];
    #pragma unroll
    for (int k = 1; k < 10; ++k) mx = fmaxf(mx, a[k]);
    mx = fmaxf(mx, dppf<DPP_ROW_SHR1>(mx));
    mx = fmaxf(mx, dppf<DPP_ROW_SHR2>(mx));
    mx = fmaxf(mx, dppf<DPP_ROW_SHR4>(mx));
    mx = fmaxf(mx, dppf<DPP_ROW_SHR8>(mx));
    mx = fmaxf(mx, dppf<DPP_BCAST15>(mx));
    mx = fmaxf(mx, dppf<DPP_BCAST31>(mx));   // lane 63 = wave max
    const unsigned mb = (unsigned)__builtin_amdgcn_readlane(__float_as_uint(mx), 63);
    const int ks = (mb != 0u) ? (250 - (int)(mb >> 23)) : 0;
    #pragma unroll
    for (int k = 0; k < 10; ++k) a[k] = ldexpf(a[k], ks);
    K += ks;
    return ks;
}

// Fused, single-dispatch. 1 block / batch element, 16 waves:
//   wid 0 = fwd consumer (+ join + global write; block 0 also reduces)
//   wid 1 = bwd consumer
//   wid {2,3,6,7}    = fwd gatherers  (SIMDs 2,3 under round-robin wid&3)
//   wid {10,11,14,15}= bwd gatherers  (SIMDs 2,3)
//   wid {4,5,8,9,12,13} exit -> consumers own SIMD0/SIMD1 issue slots.
__global__ __launch_bounds__(1024) void ctc_fused8(
    const float* __restrict__ lp,      // [B,T,V] natural-log softmax
    const int* __restrict__ in_len,    // [B]
    const int* __restrict__ tgt,       // [B,S]
    const int* __restrict__ tgt_len,   // [B]
    float* __restrict__ wloss,         // [B]  global scratch
    int* __restrict__ wflag,           // [B]  global scratch (poisoned != MAGIC)
    float* __restrict__ out)           // [1]
{
    const int b    = blockIdx.x;
    const int tid  = threadIdx.x;
    const int wid  = tid >> 6;
    const int lane = tid & 63;

    __shared__ float ringF[GRING * ROWF];    // 48 KB
    __shared__ float ringB[GRING * ROWF];    // 48 KB
    __shared__ float dumpB[640];
    __shared__ int   tagF[8], tagB[8];
    __shared__ int   consF, consB;
    __shared__ int   KBsh;

    const int L  = tgt_len[b];        // 64..256
    const int Tb = in_len[b];         // 768..1024
    const float* lpb = lp + (size_t)b * T_ * V_;
    const int* tg = tgt + b * S_;

    const int tm = (Tb - 2) >> 1;
    const int Uf = tm;                // fwd steps: u=1..Uf (row t=u) -> alpha_tm
    const int Ub = Tb - 2 - tm;       // bwd steps: u=1..Ub (row t=Tb-1-u) -> g_{tm+1}

    if (tid == 0) { consF = 0; consB = 0; }
    if (tid < 8) tagF[tid] = -1;
    else if (tid < 16) tagB[tid - 8] = -1;
    __syncthreads();                  // executed by all 16 waves, then 6 exit

    if (wid == 4 || wid == 5 || wid == 8 || wid == 9 || wid == 12 || wid == 13)
        return;                       // filler waves: free SIMD0/1 issue slots

    if (wid >= 2) {
        // ======================= gatherers =======================
        const int gi  = (wid >> 2) * 2 + (wid & 1);   // {2,3,6,7}->0..3, {10,11,14,15}->4..7
        const int dir = (gi >= 4) ? 1 : 0;
        const int q   = dir ? (gi - 4) : gi;
        const int U   = dir ? Ub : Uf;
        float* ring   = dir ? ringB : ringF;
        int*   tags   = dir ? tagB  : tagF;
        int*   consp  = dir ? &consB : &consF;

        int   labE[5];
        float vmask[5];
        #pragma unroll
        for (int c = 0; c < 5; ++c) {
            const int j = 5 * lane + c;
            if (j < L) { labE[c] = tg[j]; vmask[c] = 1.0f; }
            else       { labE[c] = 0;     vmask[c] = 0.0f; }
        }

        float vA[4][6], vB[4][6];
        auto issueLoads = [&](float (&v)[4][6], int m) {
            const int n = min(4, U - 4 * m);
            #pragma unroll
            for (int r = 0; r < 4; ++r) {
                if (r < n) {
                    const int u = 4 * m + 1 + r;
                    const int t = dir ? (Tb - 1 - u) : u;
                    const float* row = lpb + (size_t)t * V_;
                    v[r][0] = row[0];
                    #pragma unroll
                    for (int c = 0; c < 5; ++c) v[r][c + 1] = row[labE[c]];
                }
            }
        };
        auto processBlock = [&](float (&v)[4][6], int m) {
            const int n = min(4, U - 4 * m);
            // ring-slot reuse gate: slot shared with block m-8
            while (__hip_atomic_load(consp, __ATOMIC_RELAXED, WG_SCOPE) < 4 * m - 28)
                __builtin_amdgcn_s_sleep(1);
            #pragma unroll
            for (int r = 0; r < 4; ++r) {
                if (r < n) {
                    const int u = 4 * m + 1 + r;
                    float e[6];
                    e[0] = __builtin_exp2f(v[r][0] * INV_LN2);
                    #pragma unroll
                    for (int c = 0; c < 5; ++c)
                        e[c + 1] = vmask[c] * __builtin_exp2f(v[r][c + 1] * INV_LN2);
                    float* rb = ring + ((u - 1) & (GRING - 1)) * ROWF;
                    ((float2*)rb)[lane]         = make_float2(e[0], e[1]);
                    ((float2*)(rb + 128))[lane] = make_float2(e[2], e[3]);
                    ((float2*)(rb + 256))[lane] = make_float2(e[4], e[5]);
                }
            }
            if (lane == 0)
                __hip_atomic_store(&tags[m & 7], m, __ATOMIC_RELEASE, WG_SCOPE);
        };

        // software pipeline: one block of gathers always in flight ahead
        int mA = q;
        bool haveA = (4 * mA + 1 <= U);
        if (haveA) issueLoads(vA, mA);
        while (haveA) {
            const int mB = mA + NGW;
            const bool haveB = (4 * mB + 1 <= U);
            if (haveB) issueLoads(vB, mB);
            processBlock(vA, mA);
            const int mA2 = mB + NGW;
            const bool haveA2 = (4 * mA2 + 1 <= U);
            if (haveA2) issueLoads(vA, mA2);
            if (haveB) processBlock(vB, mB);
            mA = mA2; haveA = haveA2;
        }
        return;
    }

    if (wid == 1) {
        // ======================= backward consumer =======================
        float sB[5];
        #pragma unroll
        for (int c = 0; c < 5; ++c) {
            const int j = 5 * lane + c + 1;
            sB[c] = (j < L && tg[j] != tg[j - 1]) ? 1.0f : 0.0f;
        }
        float g[10];
        #pragma unroll
        for (int k = 0; k < 10; ++k) g[k] = 0.0f;
        {   // g_{Tb-1}: nonzero at s=2L (blank) and s=2L-1 (last label)
            const float pb = __builtin_exp2f(lpb[(size_t)(Tb - 1) * V_] * INV_LN2);
            const float pl = __builtin_exp2f(lpb[(size_t)(Tb - 1) * V_ + tg[L - 1]] * INV_LN2);
            #pragma unroll
            for (int k = 0; k < 10; ++k) {
                const int s = 10 * lane + k;
                if (s == 2 * L)     g[k] = pb;
                if (s == 2 * L - 1) g[k] = pl;
            }
        }
        float d0n = dppf<DPP_WAVE_SHL1>(g[0]);
        float d1n = dppf<DPP_WAVE_SHL1>(g[1]);
        int K = 0;

        float2 S0[12], S1[12];                 // two 4-row sets, const-indexed
        auto readBlock = [&](float2 (&S)[12], int m) {
            const int base = ((4 * m) & (GRING - 1)) * ROWF + 2 * lane;
            #pragma unroll
            for (int r = 0; r < 4; ++r)
                #pragma unroll
                for (int pl = 0; pl < 3; ++pl)
                    S[r * 3 + pl] = *(const float2*)&ringB[base + r * ROWF + pl * 128];
        };
        auto rowCore = [&](float2 c0, float2 c1, float2 c2) {
            const float d0 = d0n, d1 = d1n;
            const float p0 = c0.x;
            g[0] = (g[0] + g[1]) * p0;
            g[1] = (g[1] + g[2] + sB[0] * g[3]) * c0.y;
            d0n = dppf<DPP_WAVE_SHL1>(g[0]);
            d1n = dppf<DPP_WAVE_SHL1>(g[1]);
            g[2] = (g[2] + g[3]) * p0;
            g[3] = (g[3] + g[4] + sB[1] * g[5]) * c1.x;
            g[4] = (g[4] + g[5]) * p0;
            g[5] = (g[5] + g[6] + sB[2] * g[7]) * c1.y;
            g[6] = (g[6] + g[7]) * p0;
            g[7] = (g[7] + g[8] + sB[3] * g[9]) * c2.x;
            g[8] = (g[8] + g[9]) * p0;
            g[9] = (g[9] + d0 + sB[4] * d1) * c2.y;
        };
        auto row4 = [&](float2 (&S)[12]) {
            #pragma unroll
            for (int r = 0; r < 4; ++r) rowCore(S[r * 3], S[r * 3 + 1], S[r * 3 + 2]);
        };

        const int FB = Ub >> 2;                // full 4-row blocks (>=95)
        poll_eq(&tagB[0], 0); readBlock(S0, 0);
        int mb = 0;
        for (; mb + 2 <= FB; mb += 2) {
            if (mb + 1 < FB) { poll_eq(&tagB[(mb + 1) & 7], mb + 1); readBlock(S1, mb + 1); }
            row4(S0);
            if (lane == 0) __hip_atomic_store(&consB, 4 * mb + 4, __ATOMIC_RELAXED, WG_SCOPE);
            if (mb + 2 < FB) { poll_eq(&tagB[(mb + 2) & 7], mb + 2); readBlock(S0, mb + 2); }
            row4(S1);
            if (lane == 0) __hip_atomic_store(&consB, 4 * mb + 8, __ATOMIC_RELAXED, WG_SCOPE);
            { const int ks = wave_rescale(g, K);
              d0n = ldexpf(d0n, ks); d1n = ldexpf(d1n, ks); }     // 8-row period
        }
        if (mb < FB) {                         // FB odd: last full block is in S0
            row4(S0);
            if (lane == 0) __hip_atomic_store(&consB, 4 * mb + 4, __ATOMIC_RELAXED, WG_SCOPE);
            { const int ks = wave_rescale(g, K);
              d0n = ldexpf(d0n, ks); d1n = ldexpf(d1n, ks); }
        }
        for (int u = 4 * FB + 1; u <= Ub; ++u) {   // remainder rows (<=3)
            poll_eq(&tagB[FB & 7], FB);
            const int base = ((u - 1) & (GRING - 1)) * ROWF + 2 * lane;
            rowCore(*(const float2*)&ringB[base],
                    *(const float2*)&ringB[base + 128],
                    *(const float2*)&ringB[base + 256]);
        }

        {   // combine: gext[s] = g[s] + g[s+1] + skip[s+2]*g[s+2] (ascending)
            const float d0 = d0n, d1 = d1n;
            g[0] = g[0] + g[1];
            g[1] = g[1] + g[2] + sB[0] * g[3];
            g[2] = g[2] + g[3];
            g[3] = g[3] + g[4] + sB[1] * g[5];
            g[4] = g[4] + g[5];
            g[5] = g[5] + g[6] + sB[2] * g[7];
            g[6] = g[6] + g[7];
            g[7] = g[7] + g[8] + sB[3] * g[9];
            g[8] = g[8] + g[9];
            g[9] = g[9] + d0 + sB[4] * d1;
        }
        #pragma unroll
        for (int k = 0; k < 10; ++k) dumpB[10 * lane + k] = g[k];
        if (lane == 0) {
            KBsh = K;
            // ds ops retire in order per wave -> consB store publishes dumpB/KBsh
            __hip_atomic_store(&consB, Ub + 64, __ATOMIC_RELAXED, WG_SCOPE);
        }
        return;
    }

    // ======================= forward consumer (wid 0) =======================
    float skipf[5];
    #pragma unroll
    for (int c = 0; c < 5; ++c) {
        const int j = 5 * lane + c;
        skipf[c] = (j >= 1 && j < L && tg[j] != tg[j - 1]) ? 1.0f : 0.0f;
    }
    float a[10];
    #pragma unroll
    for (int k = 0; k < 10; ++k) a[k] = 0.0f;
    {
        const float p00 = __builtin_exp2f(lpb[0] * INV_LN2);
        const float p01 = __builtin_exp2f(lpb[tg[0]] * INV_LN2);
        if (lane == 0) { a[0] = p00; a[1] = p01; }
    }
    float u9n = 0.0f;
    int K = 0;

    float2 S0[12], S1[12];
    auto readBlock = [&](float2 (&S)[12], int m) {
        const int base = ((4 * m) & (GRING - 1)) * ROWF + 2 * lane;
        #pragma unroll
        for (int r = 0; r < 4; ++r)
            #pragma unroll
            for (int pl = 0; pl < 3; ++pl)
                S[r * 3 + pl] = *(const float2*)&ringF[base + r * ROWF + pl * 128];
    };
    auto rowCore = [&](float2 c0, float2 c1, float2 c2) {
        const float u9 = u9n;
        const float p0 = c0.x;
        a[9] = (a[9] + a[8] + skipf[4] * a[7]) * c2.y;
        u9n = dppf<DPP_WAVE_SHR1>(a[9]);
        a[8] = (a[8] + a[7]) * p0;
        a[7] = (a[7] + a[6] + skipf[3] * a[5]) * c2.x;
        a[6] = (a[6] + a[5]) * p0;
        a[5] = (a[5] + a[4] + skipf[2] * a[3]) * c1.y;
        a[4] = (a[4] + a[3]) * p0;
        a[3] = (a[3] + a[2] + skipf[1] * a[1]) * c1.x;
        a[2] = (a[2] + a[1]) * p0;
        a[1] = (a[1] + a[0] + skipf[0] * u9) * c0.y;
        a[0] = (a[0] + u9) * p0;
    };
    auto row4 = [&](float2 (&S)[12]) {
        #pragma unroll
        for (int r = 0; r < 4; ++r) rowCore(S[r * 3], S[r * 3 + 1], S[r * 3 + 2]);
    };

    const int FB = Uf >> 2;
    poll_eq(&tagF[0], 0); readBlock(S0, 0);
    int mb = 0;
    for (; mb + 2 <= FB; mb += 2) {
        if (mb + 1 < FB) { poll_eq(&tagF[(mb + 1) & 7], mb + 1); readBlock(S1, mb + 1); }
        row4(S0);
        if (lane == 0) __hip_atomic_store(&consF, 4 * mb + 4, __ATOMIC_RELAXED, WG_SCOPE);
        if (mb + 2 < FB) { poll_eq(&tagF[(mb + 2) & 7], mb + 2); readBlock(S0, mb + 2); }
        row4(S1);
        if (lane == 0) __hip_atomic_store(&consF, 4 * mb + 8, __ATOMIC_RELAXED, WG_SCOPE);
        { const int ks = wave_rescale(a, K); u9n = ldexpf(u9n, ks); }
    }
    if (mb < FB) {
        row4(S0);
        if (lane == 0) __hip_atomic_store(&consF, 4 * mb + 4, __ATOMIC_RELAXED, WG_SCOPE);
        { const int ks = wave_rescale(a, K); u9n = ldexpf(u9n, ks); }
    }
    for (int u = 4 * FB + 1; u <= Uf; ++u) {
        poll_eq(&tagF[FB & 7], FB);
        const int base = ((u - 1) & (GRING - 1)) * ROWF + 2 * lane;
        rowCore(*(const float2*)&ringF[base],
                *(const float2*)&ringF[base + 128],
                *(const float2*)&ringF[base + 256]);
    }
    if (lane == 0) __hip_atomic_store(&consF, Uf + 64, __ATOMIC_RELAXED, WG_SCOPE);

    // ---- join: wait for bwd consumer, dot in DOUBLE (R7 lesson) ----
    poll_ge(&consB, Ub + 64);
    double sum = 0.0;
    #pragma unroll
    for (int k = 0; k < 10; ++k)
        sum += (double)a[k] * (double)dumpB[10 * lane + k];
    #pragma unroll
    for (int d = 1; d < 64; d <<= 1) sum += __shfl_xor(sum, d, 64);

    if (lane == 0) {
        float loss = 0.0f;                     // infeasible (sum<=0) -> 0
        if (sum > 0.0) {
            const long long ub2 = __double_as_longlong(sum);
            const int ex = (int)((ub2 >> 52) & 2047) - 1023;
            const double f = __longlong_as_double(
                (ub2 & 0x000FFFFFFFFFFFFFLL) | 0x3FF0000000000000LL);
            const float ll2 = __builtin_log2f((float)f) + (float)(ex - K - KBsh);
            loss = -(ll2 * LN2);
            if (!(loss <= 1e29f)) loss = 0.0f; // zero_infinity
        }
        wloss[b] = loss / (float)L;
        __hip_atomic_store(&wflag[b], (int)MAGIC, __ATOMIC_RELEASE, AG_SCOPE);
    }

    // ---- block 0: final mean over 64 batch losses (single-dispatch reduce).
    // 64 blocks on 256 idle CUs are co-resident, so the spin cannot deadlock.
    if (b == 0) {
        while ((unsigned)__hip_atomic_load(&wflag[lane], __ATOMIC_ACQUIRE, AG_SCOPE) != MAGIC)
            __builtin_amdgcn_s_sleep(1);
        float v = wloss[lane];                 // ordered after own flag's acquire
        #pragma unroll
        for (int o = 1; o < 64; o <<= 1) v += __shfl_xor(v, o, 64);
        if (lane == 0) out[0] = v / (float)B_;
    }
}

extern "C" void kernel_launch(void* const* d_in, const int* in_sizes, int n_in,
                              void* d_out, int out_size, void* d_ws, size_t ws_size,
                              hipStream_t stream) {
    const float* lp      = (const float*)d_in[0];
    const int*   in_len  = (const int*)d_in[1];
    const int*   tgt     = (const int*)d_in[2];
    const int*   tgt_len = (const int*)d_in[3];
    float* wloss = (float*)d_ws;                       // 64 floats
    int*   wflag = (int*)((char*)d_ws + 256);          // 64 ints
    float* out   = (float*)d_out;

    ctc_fused8<<<B_, 1024, 0, stream>>>(lp, in_len, tgt, tgt_len, wloss, wflag, out);
}

// Round 13
// 142.441 us; speedup vs baseline: 1.0036x; 1.0036x over previous
//
#include <hip/hip_runtime.h>

// Problem constants (fixed by setup_inputs): B=64, T=1024, V=128, S=256
constexpr int B_ = 64;
constexpr int T_ = 1024;
constexpr int V_ = 128;
constexpr int S_ = 256;
constexpr int GRING = 32;            // staged rows per direction (8 blocks of 4)
constexpr int ROWF = 384;            // floats per staged row: 3 planes x 64 lanes x float2
constexpr int NGW = 4;               // gather waves per direction
constexpr float INV_LN2 = 1.4426950408889634f;
constexpr float LN2 = 0.6931471805599453f;
constexpr unsigned MAGIC = 0x5AD0F00Du;   // != 0xAAAAAAAA poison, != 0

#define WG_SCOPE __HIP_MEMORY_SCOPE_WORKGROUP
#define AG_SCOPE __HIP_MEMORY_SCOPE_AGENT

// DPP cross-lane move (VALU pipe). old=0, bound_ctrl=false: OOB source -> 0.
template<int CTRL>
__device__ __forceinline__ float dppf(float x) {
    return __int_as_float(__builtin_amdgcn_update_dpp(
        0, __float_as_int(x), CTRL, 0xF, 0xF, false));
}
constexpr int DPP_WAVE_SHR1 = 0x138;   // lane i <- lane i-1 (lane 0 -> 0)
constexpr int DPP_WAVE_SHL1 = 0x130;   // lane i <- lane i+1 (lane 63 -> 0)
constexpr int DPP_ROW_SHR1  = 0x111;
constexpr int DPP_ROW_SHR2  = 0x112;
constexpr int DPP_ROW_SHR4  = 0x114;
constexpr int DPP_ROW_SHR8  = 0x118;
constexpr int DPP_BCAST15   = 0x142;
constexpr int DPP_BCAST31   = 0x143;

__device__ __forceinline__ float bperm(int byte_idx, float v) {
    return __int_as_float(__builtin_amdgcn_ds_bpermute(byte_idx, __float_as_int(v)));
}

__device__ __forceinline__ void poll_eq(int* p, int want) {
    // RELAXED: ds ops retire in order per wave, LDS physically shared ->
    // a visible tag implies the producer's earlier ds_writes retired.
    while (__hip_atomic_load(p, __ATOMIC_RELAXED, WG_SCOPE) != want)
        __builtin_amdgcn_s_sleep(1);
}
__device__ __forceinline__ void poll_ge(int* p, int want) {
    while (__hip_atomic_load(p, __ATOMIC_RELAXED, WG_SCOPE) < want)
        __builtin_amdgcn_s_sleep(1);
}

// Wave-uniform rescale via DPP max-reduce: pin wave max into [2^123, 2^124).
// R8/R10-proven numerics (8-row period; R9's 16-row variant underflows).
__device__ __forceinline__ int wave_rescale(float a[10], int& K) {
    float mx = a[0];
    #pragma unroll
    for (int k = 1; k < 10; ++k) mx = fmaxf(mx, a[k]);
    mx = fmaxf(mx, dppf<DPP_ROW_SHR1>(mx));
    mx = fmaxf(mx, dppf<DPP_ROW_SHR2>(mx));
    mx = fmaxf(mx, dppf<DPP_ROW_SHR4>(mx));
    mx = fmaxf(mx, dppf<DPP_ROW_SHR8>(mx));
    mx = fmaxf(mx, dppf<DPP_BCAST15>(mx));
    mx = fmaxf(mx, dppf<DPP_BCAST31>(mx));   // lane 63 = wave max
    const unsigned mb = (unsigned)__builtin_amdgcn_readlane(__float_as_uint(mx), 63);
    const int ks = (mb != 0u) ? (250 - (int)(mb >> 23)) : 0;
    #pragma unroll
    for (int k = 0; k < 10; ++k) a[k] = ldexpf(a[k], ks);
    K += ks;
    return ks;
}

// Fused, single-dispatch. 1 block / batch element, 16 waves:
//   wid 0 = fwd consumer (+ join + global write; block 0 also reduces)
//   wid 1 = bwd consumer
//   wid {2,3,6,7}    = fwd gatherers   (SIMDs 2,3 under round-robin wid&3)
//   wid {10,11,14,15}= bwd gatherers   (SIMDs 2,3)
//   wid {4,5,8,9,12,13} exit -> consumers own SIMD0/SIMD1 issue slots.
__global__ __launch_bounds__(1024) void ctc_fused9(
    const float* __restrict__ lp,      // [B,T,V] natural-log softmax
    const int* __restrict__ in_len,    // [B]
    const int* __restrict__ tgt,       // [B,S]
    const int* __restrict__ tgt_len,   // [B]
    float* __restrict__ wloss,         // [B]  global scratch
    int* __restrict__ wflag,           // [B]  global scratch (poisoned != MAGIC)
    float* __restrict__ out)           // [1]
{
    const int b    = blockIdx.x;
    const int tid  = threadIdx.x;
    const int wid  = tid >> 6;
    const int lane = tid & 63;

    __shared__ float ringF[GRING * ROWF];    // 48 KB
    __shared__ float ringB[GRING * ROWF];    // 48 KB
    __shared__ float dumpB[640];
    __shared__ int   tagF[8], tagB[8];
    __shared__ int   consF, consB;
    __shared__ int   KBsh;

    const int L  = tgt_len[b];        // 64..256
    const int Tb = in_len[b];         // 768..1024
    const float* lpb = lp + (size_t)b * T_ * V_;
    const int* tg = tgt + b * S_;

    const int tm = (Tb - 2) >> 1;
    const int Uf = tm;                // fwd steps: u=1..Uf (row t=u) -> alpha_tm
    const int Ub = Tb - 2 - tm;       // bwd steps: u=1..Ub (row t=Tb-1-u) -> g_{tm+1}

    if (tid == 0) { consF = 0; consB = 0; }
    if (tid < 8) tagF[tid] = -1;
    else if (tid < 16) tagB[tid - 8] = -1;
    __syncthreads();                  // executed by all 16 waves, then 6 exit

    if (wid == 4 || wid == 5 || wid == 8 || wid == 9 || wid == 12 || wid == 13)
        return;                       // filler waves: free SIMD0/1 issue slots

    if (wid >= 2) {
        // ======================= gatherers =======================
        // Coalesced row loads (lane l holds cols 2l, 2l+1) + in-wave
        // ds_bpermute gather: zero scattered global addresses (TA divergence
        // was the R12 suspect — 64 distinct addresses per load instruction).
        const int gi  = (wid >> 2) * 2 + (wid & 1);   // {2,3,6,7}->0..3, {10,11,14,15}->4..7
        const int dir = (gi >= 4) ? 1 : 0;
        const int q   = dir ? (gi - 4) : gi;
        const int U   = dir ? Ub : Uf;
        float* ring   = dir ? ringB : ringF;
        int*   tags   = dir ? tagB  : tagF;
        int*   consp  = dir ? &consB : &consF;

        int   bidx[5];                 // bpermute byte index = (labE>>1)*4
        float oddc[5];                 // 1.0 if odd column (take .y), else 0
        float vmask[5];
        #pragma unroll
        for (int c = 0; c < 5; ++c) {
            const int j = 5 * lane + c;
            const int lab = (j < L) ? tg[j] : 0;
            bidx[c]  = (lab >> 1) << 2;
            oddc[c]  = (lab & 1) ? 1.0f : 0.0f;
            vmask[c] = (j < L) ? 1.0f : 0.0f;
        }

        float2 vA[4], vB[4];
        auto issueLoads = [&](float2 (&v)[4], int m) {
            const int n = min(4, U - 4 * m);
            #pragma unroll
            for (int r = 0; r < 4; ++r) {
                if (r < n) {
                    const int u = 4 * m + 1 + r;
                    const int t = dir ? (Tb - 1 - u) : u;
                    v[r] = ((const float2*)(lpb + (size_t)t * V_))[lane];  // coalesced 512 B
                }
            }
        };
        auto processBlock = [&](float2 (&v)[4], int m) {
            const int n = min(4, U - 4 * m);
            // ring-slot reuse gate: slot shared with block m-8
            while (__hip_atomic_load(consp, __ATOMIC_RELAXED, WG_SCOPE) < 4 * m - 28)
                __builtin_amdgcn_s_sleep(1);
            #pragma unroll
            for (int r = 0; r < 4; ++r) {
                if (r < n) {
                    const int u = 4 * m + 1 + r;
                    float e[6];
                    e[0] = __builtin_exp2f(bperm(0, v[r].x) * INV_LN2);   // blank col 0
                    #pragma unroll
                    for (int c = 0; c < 5; ++c) {
                        const float va = bperm(bidx[c], v[r].x);
                        const float vb = bperm(bidx[c], v[r].y);
                        const float val = va + oddc[c] * (vb - va);       // select even/odd col
                        e[c + 1] = vmask[c] * __builtin_exp2f(val * INV_LN2);
                    }
                    float* rb = ring + ((u - 1) & (GRING - 1)) * ROWF;
                    ((float2*)rb)[lane]         = make_float2(e[0], e[1]);
                    ((float2*)(rb + 128))[lane] = make_float2(e[2], e[3]);
                    ((float2*)(rb + 256))[lane] = make_float2(e[4], e[5]);
                }
            }
            if (lane == 0)
                __hip_atomic_store(&tags[m & 7], m, __ATOMIC_RELEASE, WG_SCOPE);
        };

        // software pipeline: one block of loads always in flight ahead
        int mA = q;
        bool haveA = (4 * mA + 1 <= U);
        if (haveA) issueLoads(vA, mA);
        while (haveA) {
            const int mB = mA + NGW;
            const bool haveB = (4 * mB + 1 <= U);
            if (haveB) issueLoads(vB, mB);
            processBlock(vA, mA);
            const int mA2 = mB + NGW;
            const bool haveA2 = (4 * mA2 + 1 <= U);
            if (haveA2) issueLoads(vA, mA2);
            if (haveB) processBlock(vB, mB);
            mA = mA2; haveA = haveA2;
        }
        return;
    }

    if (wid == 1) {
        // ======================= backward consumer =======================
        float sB[5];
        #pragma unroll
        for (int c = 0; c < 5; ++c) {
            const int j = 5 * lane + c + 1;
            sB[c] = (j < L && tg[j] != tg[j - 1]) ? 1.0f : 0.0f;
        }
        float g[10];
        #pragma unroll
        for (int k = 0; k < 10; ++k) g[k] = 0.0f;
        {   // g_{Tb-1}: nonzero at s=2L (blank) and s=2L-1 (last label)
            const float pb = __builtin_exp2f(lpb[(size_t)(Tb - 1) * V_] * INV_LN2);
            const float pl = __builtin_exp2f(lpb[(size_t)(Tb - 1) * V_ + tg[L - 1]] * INV_LN2);
            #pragma unroll
            for (int k = 0; k < 10; ++k) {
                const int s = 10 * lane + k;
                if (s == 2 * L)     g[k] = pb;
                if (s == 2 * L - 1) g[k] = pl;
            }
        }
        float d0n = dppf<DPP_WAVE_SHL1>(g[0]);
        float d1n = dppf<DPP_WAVE_SHL1>(g[1]);
        int K = 0;

        float2 S0[12], S1[12];
        auto readBlock = [&](float2 (&S)[12], int m) {
            const int base = ((4 * m) & (GRING - 1)) * ROWF + 2 * lane;
            #pragma unroll
            for (int r = 0; r < 4; ++r)
                #pragma unroll
                for (int pl = 0; pl < 3; ++pl)
                    S[r * 3 + pl] = *(const float2*)&ringB[base + r * ROWF + pl * 128];
        };
        auto rowCore = [&](float2 c0, float2 c1, float2 c2) {
            const float d0 = d0n, d1 = d1n;
            const float p0 = c0.x;
            g[0] = (g[0] + g[1]) * p0;
            g[1] = (g[1] + g[2] + sB[0] * g[3]) * c0.y;
            d0n = dppf<DPP_WAVE_SHL1>(g[0]);
            d1n = dppf<DPP_WAVE_SHL1>(g[1]);
            g[2] = (g[2] + g[3]) * p0;
            g[3] = (g[3] + g[4] + sB[1] * g[5]) * c1.x;
            g[4] = (g[4] + g[5]) * p0;
            g[5] = (g[5] + g[6] + sB[2] * g[7]) * c1.y;
            g[6] = (g[6] + g[7]) * p0;
            g[7] = (g[7] + g[8] + sB[3] * g[9]) * c2.x;
            g[8] = (g[8] + g[9]) * p0;
            g[9] = (g[9] + d0 + sB[4] * d1) * c2.y;
        };
        auto row4 = [&](float2 (&S)[12]) {
            #pragma unroll
            for (int r = 0; r < 4; ++r) rowCore(S[r * 3], S[r * 3 + 1], S[r * 3 + 2]);
        };

        const int FB = Ub >> 2;                // full 4-row blocks (>=95)
        poll_eq(&tagB[0], 0); readBlock(S0, 0);
        int mb = 0;
        for (; mb + 2 <= FB; mb += 2) {
            // tag mb+1 needed now: first iter polls; later iters pre-confirmed (spB)
            if (mb + 1 < FB) readBlock(S1, mb + 1);
            // speculative tag read for mb+2, latency hidden behind row4(S0)
            int spA = (mb + 2 < FB)
                ? __hip_atomic_load(&tagB[(mb + 2) & 7], __ATOMIC_RELAXED, WG_SCOPE) : 0;
            __builtin_amdgcn_sched_barrier(0);   // pin reads before row work
            row4(S0);
            if (lane == 0) __hip_atomic_store(&consB, 4 * mb + 4, __ATOMIC_RELAXED, WG_SCOPE);
            if (mb + 2 < FB) {
                if (spA != mb + 2) poll_eq(&tagB[(mb + 2) & 7], mb + 2);
                readBlock(S0, mb + 2);
            }
            int spB = (mb + 3 < FB)
                ? __hip_atomic_load(&tagB[(mb + 3) & 7], __ATOMIC_RELAXED, WG_SCOPE) : 0;
            __builtin_amdgcn_sched_barrier(0);
            row4(S1);
            if (lane == 0) __hip_atomic_store(&consB, 4 * mb + 8, __ATOMIC_RELAXED, WG_SCOPE);
            { const int ks = wave_rescale(g, K);
              d0n = ldexpf(d0n, ks); d1n = ldexpf(d1n, ks); }     // 8-row period
            if (mb + 3 < FB && spB != mb + 3) poll_eq(&tagB[(mb + 3) & 7], mb + 3);
        }
        if (mb < FB) {                         // FB odd: last full block is in S0
            row4(S0);
            if (lane == 0) __hip_atomic_store(&consB, 4 * mb + 4, __ATOMIC_RELAXED, WG_SCOPE);
            { const int ks = wave_rescale(g, K);
              d0n = ldexpf(d0n, ks); d1n = ldexpf(d1n, ks); }
        }
        for (int u = 4 * FB + 1; u <= Ub; ++u) {   // remainder rows (<=3)
            poll_eq(&tagB[FB & 7], FB);
            const int base = ((u - 1) & (GRING - 1)) * ROWF + 2 * lane;
            rowCore(*(const float2*)&ringB[base],
                    *(const float2*)&ringB[base + 128],
                    *(const float2*)&ringB[base + 256]);
        }

        {   // combine: gext[s] = g[s] + g[s+1] + skip[s+2]*g[s+2] (ascending)
            const float d0 = d0n, d1 = d1n;
            g[0] = g[0] + g[1];
            g[1] = g[1] + g[2] + sB[0] * g[3];
            g[2] = g[2] + g[3];
            g[3] = g[3] + g[4] + sB[1] * g[5];
            g[4] = g[4] + g[5];
            g[5] = g[5] + g[6] + sB[2] * g[7];
            g[6] = g[6] + g[7];
            g[7] = g[7] + g[8] + sB[3] * g[9];
            g[8] = g[8] + g[9];
            g[9] = g[9] + d0 + sB[4] * d1;
        }
        #pragma unroll
        for (int k = 0; k < 10; ++k) dumpB[10 * lane + k] = g[k];
        if (lane == 0) {
            KBsh = K;
            // ds ops retire in order per wave -> consB store publishes dumpB/KBsh
            __hip_atomic_store(&consB, Ub + 64, __ATOMIC_RELAXED, WG_SCOPE);
        }
        return;
    }

    // ======================= forward consumer (wid 0) =======================
    float skipf[5];
    #pragma unroll
    for (int c = 0; c < 5; ++c) {
        const int j = 5 * lane + c;
        skipf[c] = (j >= 1 && j < L && tg[j] != tg[j - 1]) ? 1.0f : 0.0f;
    }
    float a[10];
    #pragma unroll
    for (int k = 0; k < 10; ++k) a[k] = 0.0f;
    {
        const float p00 = __builtin_exp2f(lpb[0] * INV_LN2);
        const float p01 = __builtin_exp2f(lpb[tg[0]] * INV_LN2);
        if (lane == 0) { a[0] = p00; a[1] = p01; }
    }
    float u9n = 0.0f;
    int K = 0;

    float2 S0[12], S1[12];
    auto readBlock = [&](float2 (&S)[12], int m) {
        const int base = ((4 * m) & (GRING - 1)) * ROWF + 2 * lane;
        #pragma unroll
        for (int r = 0; r < 4; ++r)
            #pragma unroll
            for (int pl = 0; pl < 3; ++pl)
                S[r * 3 + pl] = *(const float2*)&ringF[base + r * ROWF + pl * 128];
    };
    auto rowCore = [&](float2 c0, float2 c1, float2 c2) {
        const float u9 = u9n;
        const float p0 = c0.x;
        a[9] = (a[9] + a[8] + skipf[4] * a[7]) * c2.y;
        u9n = dppf<DPP_WAVE_SHR1>(a[9]);
        a[8] = (a[8] + a[7]) * p0;
        a[7] = (a[7] + a[6] + skipf[3] * a[5]) * c2.x;
        a[6] = (a[6] + a[5]) * p0;
        a[5] = (a[5] + a[4] + skipf[2] * a[3]) * c1.y;
        a[4] = (a[4] + a[3]) * p0;
        a[3] = (a[3] + a[2] + skipf[1] * a[1]) * c1.x;
        a[2] = (a[2] + a[1]) * p0;
        a[1] = (a[1] + a[0] + skipf[0] * u9) * c0.y;
        a[0] = (a[0] + u9) * p0;
    };
    auto row4 = [&](float2 (&S)[12]) {
        #pragma unroll
        for (int r = 0; r < 4; ++r) rowCore(S[r * 3], S[r * 3 + 1], S[r * 3 + 2]);
    };

    const int FB = Uf >> 2;
    poll_eq(&tagF[0], 0); readBlock(S0, 0);
    int mb = 0;
    for (; mb + 2 <= FB; mb += 2) {
        if (mb + 1 < FB) readBlock(S1, mb + 1);
        int spA = (mb + 2 < FB)
            ? __hip_atomic_load(&tagF[(mb + 2) & 7], __ATOMIC_RELAXED, WG_SCOPE) : 0;
        __builtin_amdgcn_sched_barrier(0);
        row4(S0);
        if (lane == 0) __hip_atomic_store(&consF, 4 * mb + 4, __ATOMIC_RELAXED, WG_SCOPE);
        if (mb + 2 < FB) {
            if (spA != mb + 2) poll_eq(&tagF[(mb + 2) & 7], mb + 2);
            readBlock(S0, mb + 2);
        }
        int spB = (mb + 3 < FB)
            ? __hip_atomic_load(&tagF[(mb + 3) & 7], __ATOMIC_RELAXED, WG_SCOPE) : 0;
        __builtin_amdgcn_sched_barrier(0);
        row4(S1);
        if (lane == 0) __hip_atomic_store(&consF, 4 * mb + 8, __ATOMIC_RELAXED, WG_SCOPE);
        { const int ks = wave_rescale(a, K); u9n = ldexpf(u9n, ks); }
        if (mb + 3 < FB && spB != mb + 3) poll_eq(&tagF[(mb + 3) & 7], mb + 3);
    }
    if (mb < FB) {
        row4(S0);
        if (lane == 0) __hip_atomic_store(&consF, 4 * mb + 4, __ATOMIC_RELAXED, WG_SCOPE);
        { const int ks = wave_rescale(a, K); u9n = ldexpf(u9n, ks); }
    }
    for (int u = 4 * FB + 1; u <= Uf; ++u) {
        poll_eq(&tagF[FB & 7], FB);
        const int base = ((u - 1) & (GRING - 1)) * ROWF + 2 * lane;
        rowCore(*(const float2*)&ringF[base],
                *(const float2*)&ringF[base + 128],
                *(const float2*)&ringF[base + 256]);
    }
    if (lane == 0) __hip_atomic_store(&consF, Uf + 64, __ATOMIC_RELAXED, WG_SCOPE);

    // ---- join: wait for bwd consumer, dot in DOUBLE (R7 lesson) ----
    poll_ge(&consB, Ub + 64);
    double sum = 0.0;
    #pragma unroll
    for (int k = 0; k < 10; ++k)
        sum += (double)a[k] * (double)dumpB[10 * lane + k];
    #pragma unroll
    for (int d = 1; d < 64; d <<= 1) sum += __shfl_xor(sum, d, 64);

    if (lane == 0) {
        float loss = 0.0f;                     // infeasible (sum<=0) -> 0
        if (sum > 0.0) {
            const long long ub2 = __double_as_longlong(sum);
            const int ex = (int)((ub2 >> 52) & 2047) - 1023;
            const double f = __longlong_as_double(
                (ub2 & 0x000FFFFFFFFFFFFFLL) | 0x3FF0000000000000LL);
            const float ll2 = __builtin_log2f((float)f) + (float)(ex - K - KBsh);
            loss = -(ll2 * LN2);
            if (!(loss <= 1e29f)) loss = 0.0f; // zero_infinity
        }
        wloss[b] = loss / (float)L;
        __hip_atomic_store(&wflag[b], (int)MAGIC, __ATOMIC_RELEASE, AG_SCOPE);
    }

    // ---- block 0: final mean over 64 batch losses (single-dispatch reduce).
    // 64 blocks on 256 CUs are co-resident, so the spin cannot deadlock.
    if (b == 0) {
        while ((unsigned)__hip_atomic_load(&wflag[lane], __ATOMIC_ACQUIRE, AG_SCOPE) != MAGIC)
            __builtin_amdgcn_s_sleep(1);
        float v = wloss[lane];                 // ordered after own flag's acquire
        #pragma unroll
        for (int o = 1; o < 64; o <<= 1) v += __shfl_xor(v, o, 64);
        if (lane == 0) out[0] = v / (float)B_;
    }
}

extern "C" void kernel_launch(void* const* d_in, const int* in_sizes, int n_in,
                              void* d_out, int out_size, void* d_ws, size_t ws_size,
                              hipStream_t stream) {
    const float* lp      = (const float*)d_in[0];
    const int*   in_len  = (const int*)d_in[1];
    const int*   tgt     = (const int*)d_in[2];
    const int*   tgt_len = (const int*)d_in[3];
    float* wloss = (float*)d_ws;                       // 64 floats
    int*   wflag = (int*)((char*)d_ws + 256);          // 64 ints
    float* out   = (float*)d_out;

    ctc_fused9<<<B_, 1024, 0, stream>>>(lp, in_len, tgt, tgt_len, wloss, wflag, out);
}